// Round 15
// baseline (249.889 us; speedup 1.0000x reference)
//
#include <hip/hip_runtime.h>
#include <hip/hip_bf16.h>

// Problem constants (fixed)
#define B_ 4
#define T_ 2048
#define D_ 1024
#define H_ 16
// DK = DV = 64

typedef __attribute__((ext_vector_type(8))) short bf16x8;
typedef __attribute__((ext_vector_type(4))) float f32x4;
typedef __attribute__((ext_vector_type(4))) unsigned short u16x4;
typedef __attribute__((ext_vector_type(4))) unsigned int u32x4;

__device__ __forceinline__ unsigned short f2bf(float x) {
  union { float f; unsigned u; } v; v.f = x;
  unsigned r = v.u + 0x7fffu + ((v.u >> 16) & 1u);   // RNE
  return (unsigned short)(r >> 16);
}

__device__ __forceinline__ unsigned pack_bf2(float a, float b) {
  __hip_bfloat162 h = __float22bfloat162_rn(float2{a, b});
  union { __hip_bfloat162 h; unsigned u; } cv; cv.h = h; return cv.u;
}

__device__ __forceinline__ void gload_lds16(const void* g, void* l) {
  __builtin_amdgcn_global_load_lds(
      (const __attribute__((address_space(1))) unsigned int*)g,
      (__attribute__((address_space(3))) unsigned int*)l, 16, 0, 0);
}

#define MFMA16(a, b, c) __builtin_amdgcn_mfma_f32_16x16x32_bf16((a), (b), (c), 0, 0, 0)

// ---------------------------------------------------------------------------
// prep: activation f32->bf16 convert (3072 blocks) + weight transposes
// (1024 blocks) in ONE dispatch.
// ---------------------------------------------------------------------------
__global__ __launch_bounds__(256) void prep(
    const float4* __restrict__ Q, const float4* __restrict__ K,
    const float4* __restrict__ V, u16x4* __restrict__ Qb,
    u16x4* __restrict__ Kb, u16x4* __restrict__ Vb,
    const float* __restrict__ WQ, const float* __restrict__ WK,
    const float* __restrict__ WV, const float* __restrict__ WO,
    unsigned short* __restrict__ WqT, unsigned short* __restrict__ WkT,
    unsigned short* __restrict__ WvT, unsigned short* __restrict__ WOt) {
  __shared__ float tile[64][65];
  const int bidx = blockIdx.x;
  if (bidx < 3072) {
    const int seg = bidx >> 10;
    const int sb  = bidx & 1023;
    const float4* s = (seg == 0) ? Q : (seg == 1) ? K : V;
    u16x4* d       = (seg == 0) ? Qb : (seg == 1) ? Kb : Vb;
    int i = sb * 256 + threadIdx.x;
#pragma unroll
    for (int it = 0; it < 8; ++it, i += 262144) {   // n4 = 2097152
      float4 v = s[i];
      u16x4 o;
      o[0] = f2bf(v.x); o[1] = f2bf(v.y); o[2] = f2bf(v.z); o[3] = f2bf(v.w);
      d[i] = o;
    }
  } else {
    const int sub4 = bidx - 3072;
    const int seg = sub4 >> 8;
    const int sub = sub4 & 255;
    const float* src = (seg == 0) ? WQ : (seg == 1) ? WK : (seg == 2) ? WV : WO;
    unsigned short* dst = (seg == 0) ? WqT : (seg == 1) ? WkT : (seg == 2) ? WvT : WOt;
    const int DK = (seg == 3) ? 1024 : 64;
    int h, dt, ktile;
    if (seg == 3) { h = 0; dt = sub >> 4; ktile = sub & 15; }
    else          { h = sub >> 4; dt = sub & 15; ktile = 0; }
    const int d0 = dt * 64, k0 = ktile * 64;
    const int tx = threadIdx.x & 63, ty = threadIdx.x >> 6;
    const float* s = src + (size_t)h * 1024 * DK;
#pragma unroll
    for (int i = 0; i < 16; ++i) {
      int row = i * 4 + ty;
      tile[row][tx] = s[(size_t)(d0 + row) * DK + k0 + tx];
    }
    __syncthreads();
    unsigned short* dd = dst + (size_t)h * DK * 1024;
#pragma unroll
    for (int i = 0; i < 16; ++i) {
      int kk = i * 4 + ty;
      dd[(size_t)(k0 + kk) * 1024 + d0 + tx] = f2bf(tile[tx][kk]);
    }
  }
}

// ---------------------------------------------------------------------------
// GEMM body: C[m][n] = sum_k A[m][k] * Bt[n][k], K=1024, tile 128x128.
// All-bf16, global_load_lds width-16 both sides. SM = single 32KB buffer
// (As = SM, Bs = SM+8192) shared by all instantiations; after the k-loop it
// is reused as the C-tile for the coalesced epilogue (modes 1/2):
// acc -> LDS bf16 (XOR-swizzled rows) -> b128 reads -> contiguous 16B global
// stores. Replaces 64 scattered 2-byte global stores/thread. Mode 0 keeps
// direct f32 stores (f32 tile wouldn't fit in 32KB).
// CMODE 0: C f32 [M][1024]
// CMODE 1: C bf16 per-head [B,H,T,64]   (row = b*T+t, col = h*64+k)
// CMODE 2: C bf16 VhT [B,H,64,T]        (row = h*64+v, col = b*T+t)
// ---------------------------------------------------------------------------
template <int CMODE>
__device__ __forceinline__ void gemm_body(
    unsigned short* __restrict__ SM,
    const unsigned short* __restrict__ A, const unsigned short* __restrict__ Bt,
    void* __restrict__ C, int bid, int nTilesN, float scale) {
  unsigned short* As = SM;
  unsigned short* Bs = SM + 8192;
  const int bm = bid / nTilesN, bn = bid % nTilesN;
  const int m0 = bm * 128, n0 = bn * 128;
  const int tid = threadIdx.x;
  const int wave = tid >> 6, lane = tid & 63;
  const int wr = wave >> 1, wc = wave & 1;

  f32x4 acc[4][4];
#pragma unroll
  for (int m = 0; m < 4; ++m)
#pragma unroll
    for (int n = 0; n < 4; ++n) acc[m][n] = 0.f;

  const int soff = wave * 1024 + lane * 16;
  const char* Afr = (const char*)As + (wr * 64 + (lane & 15)) * 128 + (lane >> 4) * 16;
  const char* Bfr = (const char*)Bs + (wc * 64 + (lane & 15)) * 128 + (lane >> 4) * 16;

  for (int kt = 0; kt < 16; ++kt) {
    __syncthreads();
#pragma unroll
    for (int i = 0; i < 4; ++i) {
      int o2 = i * 4096 + soff;
      int row = o2 >> 7, colb = o2 & 127;
      gload_lds16((const char*)(A + (size_t)(m0 + row) * 1024 + kt * 64) + colb,
                  (char*)As + i * 4096 + wave * 1024);
      gload_lds16((const char*)(Bt + (size_t)(n0 + row) * 1024 + kt * 64) + colb,
                  (char*)Bs + i * 4096 + wave * 1024);
    }
    __syncthreads();
#pragma unroll
    for (int kk = 0; kk < 2; ++kk) {
      bf16x8 af[4], bf[4];
#pragma unroll
      for (int m = 0; m < 4; ++m) af[m] = *(const bf16x8*)(Afr + m * 2048 + kk * 64);
#pragma unroll
      for (int n = 0; n < 4; ++n) bf[n] = *(const bf16x8*)(Bfr + n * 2048 + kk * 64);
#pragma unroll
      for (int m = 0; m < 4; ++m)
#pragma unroll
        for (int n = 0; n < 4; ++n) acc[m][n] = MFMA16(af[m], bf[n], acc[m][n]);
    }
  }

  if constexpr (CMODE == 0) {
    const int rbase = m0 + wr * 64 + ((lane >> 4) << 2);
    const int cbase = n0 + wc * 64 + (lane & 15);
#pragma unroll
    for (int m = 0; m < 4; ++m)
#pragma unroll
      for (int n = 0; n < 4; ++n)
#pragma unroll
        for (int r = 0; r < 4; ++r) {
          int row = rbase + m * 16 + r;
          int col = cbase + n * 16;
          ((float*)C)[(size_t)row * 1024 + col] = acc[m][n][r] * scale;
        }
  } else {
    // ---- coalesced epilogue: acc -> LDS (swizzled) -> 16B global stores ----
    __syncthreads();                         // all waves done reading As/Bs
    const int rb = wr * 64 + ((lane >> 4) << 2);   // LDS row base
    const int cb = wc * 64 + (lane & 15);          // LDS col base
#pragma unroll
    for (int m = 0; m < 4; ++m)
#pragma unroll
      for (int n = 0; n < 4; ++n)
#pragma unroll
        for (int r = 0; r < 4; ++r) {
          int row = rb + m * 16 + r;
          int col = cb + n * 16;
          int byte = row * 256 + ((col * 2) ^ ((row & 7) << 4));
          *(unsigned short*)((char*)SM + byte) = f2bf(acc[m][n][r] * scale);
        }
    __syncthreads();
#pragma unroll
    for (int it = 0; it < 8; ++it) {
      int p = it * 256 + tid;                // piece: 16B of a tile row
      int row = p >> 4, q = p & 15;
      int byte = row * 256 + ((q * 16) ^ ((row & 7) << 4));
      u32x4 v = *(const u32x4*)((const char*)SM + byte);
      int row_g = m0 + row;
      size_t dst;
      if constexpr (CMODE == 1) {
        int b = row_g >> 11, t = row_g & 2047;
        int h = (n0 >> 6) + (q >> 3), k = (q & 7) * 8;
        dst = (((size_t)(b * H_ + h) * T_) + t) * 64 + k;
      } else {
        int h = row_g >> 6, vv = row_g & 63;
        int b = n0 >> 11, t = (n0 & 2047) + q * 8;
        dst = (((size_t)(b * H_ + h) * 64) + vv) * T_ + t;
      }
      *(u32x4*)((unsigned short*)C + dst) = v;
    }
  }
}

// All three projection GEMMs in ONE dispatch (1536 blocks), XCD-swizzled.
__global__ __launch_bounds__(256) void gemm_proj3(
    const unsigned short* __restrict__ Qbf, const unsigned short* __restrict__ WqT,
    unsigned short* __restrict__ Qh,
    const unsigned short* __restrict__ Kbf, const unsigned short* __restrict__ WkT,
    unsigned short* __restrict__ Kh,
    const unsigned short* __restrict__ WvT, const unsigned short* __restrict__ Vbf,
    unsigned short* __restrict__ VhT, float qscale) {
  __shared__ unsigned short SM[128 * 128];   // 32KB: staging + C-tile epilogue
  const int bid = blockIdx.x;
  const int wid = (bid & 7) * 192 + (bid >> 3);   // 1536/8 = 192, bijective
  const int seg = wid / 512, sub = wid % 512;
  if (seg == 0)      gemm_body<1>(SM, Qbf, WqT, Qh,  sub, 8,  qscale);
  else if (seg == 1) gemm_body<1>(SM, Kbf, WkT, Kh,  sub, 8,  1.0f);
  else               gemm_body<2>(SM, WvT, Vbf, VhT, sub, 64, 1.0f);
}

__global__ __launch_bounds__(256) void gemm_out(
    const unsigned short* __restrict__ A, const unsigned short* __restrict__ Bt,
    float* __restrict__ C) {
  __shared__ unsigned short SM[128 * 128];
  const int bid = blockIdx.x;
  const int wid = (bid & 7) * 64 + (bid >> 3);    // 512/8 = 64, bijective
  gemm_body<0>(SM, A, Bt, C, wid, 8, 1.0f);
}

// ---------------------------------------------------------------------------
// Flash attention (causal), v7d: fused dual-tile inner loop, __shfl_xor
// reductions (R14-proven). NO min-waves launch bound: (256,4) squeezed the
// fused loop's ~110-reg live set to VGPR=64 (spill/remat traffic, the R14
// counter); natural allocation trades at most 1 block/CU of occupancy for a
// spill-free inner loop. T12 in-register P redistribution kept.
// ---------------------------------------------------------------------------
__global__ __launch_bounds__(256) void attn_fwd(
    const unsigned short* __restrict__ Qh, const unsigned short* __restrict__ Kh,
    const unsigned short* __restrict__ VhT, unsigned short* __restrict__ Abuf) {
  __shared__ unsigned short Ks[2][64 * 64];   // [s][k], swizzled, 8KB each
  __shared__ unsigned short Vs[2][64 * 64];   // [v][s], swizzled, 8KB each

  const int bid = blockIdx.x;
  const int wid = ((bid & 7) << 7) | (bid >> 3);  // XCD swizzle (1024 % 8 == 0)
  const int p  = wid & 15;                   // pair index
  const int bh = wid >> 4;                   // b*H + h
  const int b = bh >> 4, h = bh & 15;
  const int tid = threadIdx.x;
  const int wave = tid >> 6, lane = tid & 63;
  const int lq = lane & 15;
  const int hi = lane >> 4;
  const int nkt = 32 - p;                    // heavy tile KV count

  int q0[2];
  q0[0] = (31 - p) * 64 + wave * 16;         // heavy
  q0[1] = p * 64 + wave * 16;                // light

  const char* Kbase = (const char*)(Kh + (size_t)bh * T_ * 64);
  const char* Vbase = (const char*)(VhT + (size_t)bh * 64 * T_);

  // staging geometry: linear LDS dest, inverse-swizzled global source col
  int srow[2], scol[2], sdst[2];
#pragma unroll
  for (int i = 0; i < 2; ++i) {
    int o = i * 4096 + wave * 1024 + lane * 16;
    srow[i] = o >> 7;
    scol[i] = (o & 127) ^ ((srow[i] & 7) << 4);
    sdst[i] = i * 4096 + wave * 1024;        // wave-uniform dest (HW adds lane*16)
  }

  // Q fragments per tile
  bf16x8 qf[2][2];
#pragma unroll
  for (int j = 0; j < 2; ++j) {
    const unsigned short* qp = Qh + ((size_t)bh * T_ + q0[j] + lq) * 64 + hi * 8;
    qf[j][0] = *(const bf16x8*)qp;
    qf[j][1] = *(const bf16x8*)(qp + 32);
  }

  f32x4 o[2][4];
#pragma unroll
  for (int j = 0; j < 2; ++j)
#pragma unroll
    for (int n = 0; n < 4; ++n) o[j][n] = 0.f;
  float m_run[2] = {-1e30f, -1e30f}, l_run[2] = {0.f, 0.f};

  auto stage = [&](int buf, int kt) {
#pragma unroll
    for (int i = 0; i < 2; ++i) {
      gload_lds16(Kbase + (size_t)(kt * 64 + srow[i]) * 128 + scol[i],
                  (char*)Ks[buf] + sdst[i]);
      gload_lds16(Vbase + (size_t)srow[i] * (T_ * 2) + kt * 128 + scol[i],
                  (char*)Vs[buf] + sdst[i]);
    }
  };

  // softmax + pack for one q-tile — R11/R14-proven __shfl_xor semantics
  auto softmax = [&](f32x4 (&sc)[4], f32x4 (&oj)[4], float& mr, float& lr,
                     int q0j, int s0, unsigned (&pk)[4][2]) {
    if (s0 + 63 > q0j) {                     // diagonal tile: element mask
      int qg = q0j + lq;
#pragma unroll
      for (int c = 0; c < 4; ++c)
#pragma unroll
        for (int r = 0; r < 4; ++r) {
          int sg = s0 + c * 16 + hi * 4 + r;
          if (sg > qg) sc[c][r] = -1e30f;
        }
    }
    float pmax = sc[0][0];
#pragma unroll
    for (int c = 0; c < 4; ++c)
#pragma unroll
      for (int r = 0; r < 4; ++r) pmax = fmaxf(pmax, sc[c][r]);
    pmax = fmaxf(pmax, __shfl_xor(pmax, 16));
    pmax = fmaxf(pmax, __shfl_xor(pmax, 32));

    if (!__all(pmax - mr <= 8.f)) {          // defer-max (T13): usually skip
      float mnew = fmaxf(mr, pmax);
      float corr = __builtin_amdgcn_exp2f(mr - mnew);
      float cr[4];
#pragma unroll
      for (int r = 0; r < 4; ++r) cr[r] = __shfl(corr, hi * 4 + r);
#pragma unroll
      for (int n = 0; n < 4; ++n)
#pragma unroll
        for (int r = 0; r < 4; ++r) oj[n][r] *= cr[r];
      lr *= corr;
      mr = mnew;
    }

    float psum = 0.f;
#pragma unroll
    for (int c = 0; c < 4; ++c) {
      float e0 = __builtin_amdgcn_exp2f(sc[c][0] - mr);
      float e1 = __builtin_amdgcn_exp2f(sc[c][1] - mr);
      float e2 = __builtin_amdgcn_exp2f(sc[c][2] - mr);
      float e3 = __builtin_amdgcn_exp2f(sc[c][3] - mr);
      psum += (e0 + e1) + (e2 + e3);
      pk[c][0] = pack_bf2(e0, e1);
      pk[c][1] = pack_bf2(e2, e3);
    }
    psum += __shfl_xor(psum, 16);
    psum += __shfl_xor(psum, 32);
    lr += psum;
  };

  // T12: build PV A-fragment dwords from packed P via permlane swaps
  // (distinct-value operands; end-to-end verified R7-R11/R14)
  auto mkpa = [&](unsigned (&pk)[4][2], int ks) -> bf16x8 {
    unsigned a0 = pk[2 * ks][0], b0 = pk[2 * ks + 1][0];
    unsigned a1 = pk[2 * ks][1], b1 = pk[2 * ks + 1][1];
    asm("v_permlane32_swap_b32 %0, %1" : "+v"(a0), "+v"(b0));
    asm("v_permlane16_swap_b32 %0, %1" : "+v"(a0), "+v"(b0));
    asm("v_permlane32_swap_b32 %0, %1" : "+v"(a1), "+v"(b1));
    asm("v_permlane16_swap_b32 %0, %1" : "+v"(a1), "+v"(b1));
    u32x4 pau;
    pau[0] = a0; pau[1] = a1; pau[2] = b0; pau[3] = b1;
    return __builtin_bit_cast(bf16x8, pau);
  };

  // prologue: stage tile 0
  stage(0, 0);
  asm volatile("s_waitcnt vmcnt(0)" ::: "memory");
  __builtin_amdgcn_s_barrier();

  int cur = 0;
  for (int kt = 0; kt < nkt; ++kt) {
    const int s0 = kt * 64;
    if (kt + 1 < nkt) stage(cur ^ 1, kt + 1);   // prefetch overlaps compute

    const char* KsB = (const char*)Ks[cur];
    const char* VsB = (const char*)Vs[cur];
    const bool act1 = (kt <= p);             // light tile active (block-uniform)

    // ---- fused QK^T: K fragments read once, feed both q-tiles ----
    f32x4 sc0[4], sc1[4];
    __builtin_amdgcn_s_setprio(1);
#pragma unroll
    for (int c = 0; c < 4; ++c) {
      int r = c * 16 + lq;
      const char* kb = KsB + r * 128;
      int sw = (r & 7) << 4;
      bf16x8 ka0 = *(const bf16x8*)(kb + ((hi * 16) ^ sw));
      bf16x8 ka1 = *(const bf16x8*)(kb + ((64 + hi * 16) ^ sw));
      f32x4 z0 = 0.f;
      z0 = MFMA16(ka0, qf[0][0], z0);
      sc0[c] = MFMA16(ka1, qf[0][1], z0);
      if (act1) {
        f32x4 z1 = 0.f;
        z1 = MFMA16(ka0, qf[1][0], z1);
        sc1[c] = MFMA16(ka1, qf[1][1], z1);
      }
    }
    __builtin_amdgcn_s_setprio(0);

    // ---- softmax per tile -> packed P in registers ----
    unsigned pk0[4][2], pk1[4][2];
    softmax(sc0, o[0], m_run[0], l_run[0], q0[0], s0, pk0);
    if (act1) softmax(sc1, o[1], m_run[1], l_run[1], q0[1], s0, pk1);

    // ---- fused PV: V fragments read once, feed both q-tiles ----
    __builtin_amdgcn_s_setprio(1);
#pragma unroll
    for (int ks = 0; ks < 2; ++ks) {
      bf16x8 pa0 = mkpa(pk0, ks);
      bf16x8 pa1;
      if (act1) pa1 = mkpa(pk1, ks);
#pragma unroll
      for (int n = 0; n < 4; ++n) {
        int rv = n * 16 + lq;
        bf16x8 vb = *(const bf16x8*)(VsB + rv * 128 +
                                     ((ks * 64 + hi * 16) ^ ((rv & 7) << 4)));
        o[0][n] = MFMA16(pa0, vb, o[0][n]);
        if (act1) o[1][n] = MFMA16(pa1, vb, o[1][n]);
      }
    }
    __builtin_amdgcn_s_setprio(0);

    // tile boundary: drain prefetch, sync all waves
    asm volatile("s_waitcnt vmcnt(0)" ::: "memory");
    __builtin_amdgcn_s_barrier();
    cur ^= 1;
  }

  // finalize: divide by l, write A [b*T+t][h*64+v] bf16
#pragma unroll
  for (int j = 0; j < 2; ++j) {
    float inv[4];
#pragma unroll
    for (int r = 0; r < 4; ++r)
      inv[r] = 1.0f / __shfl(l_run[j], hi * 4 + r);
#pragma unroll
    for (int r = 0; r < 4; ++r) {
      int t = q0[j] + hi * 4 + r;
      size_t base = ((size_t)b * T_ + t) * 1024 + h * 64 + lq;
#pragma unroll
      for (int n = 0; n < 4; ++n)
        Abuf[base + n * 16] = f2bf(o[j][n][r] * inv[r]);
    }
  }
}

// ---------------------------------------------------------------------------
extern "C" void kernel_launch(void* const* d_in, const int* in_sizes, int n_in,
                              void* d_out, int out_size, void* d_ws, size_t ws_size,
                              hipStream_t stream) {
  (void)in_sizes; (void)n_in; (void)out_size; (void)ws_size;
  const float* Q  = (const float*)d_in[0];
  const float* K  = (const float*)d_in[1];
  const float* V  = (const float*)d_in[2];
  const float* WQ = (const float*)d_in[3];
  const float* WK = (const float*)d_in[4];
  const float* WV = (const float*)d_in[5];
  const float* WO = (const float*)d_in[6];
  float* out = (float*)d_out;
  char* ws = (char*)d_ws;

  const size_t SZ_ACT = (size_t)8192 * 1024 * 2;  // 16.78 MB
  const size_t SZ_W   = (size_t)1024 * 1024 * 2;  //  2.10 MB
  unsigned short* Qbf = (unsigned short*)(ws);
  unsigned short* Kbf = (unsigned short*)(ws + SZ_ACT);
  unsigned short* Vbf = (unsigned short*)(ws + 2 * SZ_ACT);
  unsigned short* WqT = (unsigned short*)(ws + 3 * SZ_ACT);
  unsigned short* WkT = (unsigned short*)(ws + 3 * SZ_ACT + SZ_W);
  unsigned short* WvT = (unsigned short*)(ws + 3 * SZ_ACT + 2 * SZ_W);
  unsigned short* WOt = (unsigned short*)(ws + 3 * SZ_ACT + 3 * SZ_W);
  unsigned short* Qh  = (unsigned short*)(ws + 3 * SZ_ACT + 4 * SZ_W);
  unsigned short* Kh  = (unsigned short*)(ws + 4 * SZ_ACT + 4 * SZ_W);
  unsigned short* VhT = (unsigned short*)(ws + 5 * SZ_ACT + 4 * SZ_W);
  unsigned short* Abuf = Qbf;  // Qbf dead after Q projection

  // 1) convert activations + transpose weights (one dispatch)
  prep<<<4096, 256, 0, stream>>>((const float4*)Q, (const float4*)K,
                                 (const float4*)V, (u16x4*)Qbf, (u16x4*)Kbf,
                                 (u16x4*)Vbf, WQ, WK, WV, WO,
                                 WqT, WkT, WvT, WOt);

  // 2) projections (one dispatch, all-bf16; Q scaled by log2(e)/sqrt(dk))
  const float qscale = 1.4426950408889634f / 8.0f;
  gemm_proj3<<<1536, 256, 0, stream>>>(Qbf, WqT, Qh, Kbf, WkT, Kh,
                                       WvT, Vbf, VhT, qscale);

  // 3) causal flash attention (fused dual-tile, natural VGPR allocation)
  attn_fwd<<<1024, 256, 0, stream>>>(Qh, Kh, VhT, Abuf);

  // 4) output projection -> f32 (coalesced epilogue n/a: f32 tile > 32KB LDS)
  gemm_out<<<512, 256, 0, stream>>>(Abuf, WOt, out);
}

// Round 16
// 216.010 us; speedup vs baseline: 1.1568x; 1.1568x over previous
//
#include <hip/hip_runtime.h>
#include <hip/hip_bf16.h>

// Problem constants (fixed)
#define B_ 4
#define T_ 2048
#define D_ 1024
#define H_ 16
// DK = DV = 64

typedef __attribute__((ext_vector_type(8))) short bf16x8;
typedef __attribute__((ext_vector_type(4))) float f32x4;
typedef __attribute__((ext_vector_type(4))) unsigned short u16x4;
typedef __attribute__((ext_vector_type(4))) unsigned int u32x4;

__device__ __forceinline__ unsigned short f2bf(float x) {
  union { float f; unsigned u; } v; v.f = x;
  unsigned r = v.u + 0x7fffu + ((v.u >> 16) & 1u);   // RNE
  return (unsigned short)(r >> 16);
}

__device__ __forceinline__ unsigned pack_bf2(float a, float b) {
  __hip_bfloat162 h = __float22bfloat162_rn(float2{a, b});
  union { __hip_bfloat162 h; unsigned u; } cv; cv.h = h; return cv.u;
}

__device__ __forceinline__ void gload_lds16(const void* g, void* l) {
  __builtin_amdgcn_global_load_lds(
      (const __attribute__((address_space(1))) unsigned int*)g,
      (__attribute__((address_space(3))) unsigned int*)l, 16, 0, 0);
}

#define MFMA16(a, b, c) __builtin_amdgcn_mfma_f32_16x16x32_bf16((a), (b), (c), 0, 0, 0)

// ---------------------------------------------------------------------------
// prep: activation f32->bf16 convert (3072 blocks) + weight transposes
// (1024 blocks) in ONE dispatch.
// ---------------------------------------------------------------------------
__global__ __launch_bounds__(256) void prep(
    const float4* __restrict__ Q, const float4* __restrict__ K,
    const float4* __restrict__ V, u16x4* __restrict__ Qb,
    u16x4* __restrict__ Kb, u16x4* __restrict__ Vb,
    const float* __restrict__ WQ, const float* __restrict__ WK,
    const float* __restrict__ WV, const float* __restrict__ WO,
    unsigned short* __restrict__ WqT, unsigned short* __restrict__ WkT,
    unsigned short* __restrict__ WvT, unsigned short* __restrict__ WOt) {
  __shared__ float tile[64][65];
  const int bidx = blockIdx.x;
  if (bidx < 3072) {
    const int seg = bidx >> 10;
    const int sb  = bidx & 1023;
    const float4* s = (seg == 0) ? Q : (seg == 1) ? K : V;
    u16x4* d       = (seg == 0) ? Qb : (seg == 1) ? Kb : Vb;
    int i = sb * 256 + threadIdx.x;
#pragma unroll
    for (int it = 0; it < 8; ++it, i += 262144) {   // n4 = 2097152
      float4 v = s[i];
      u16x4 o;
      o[0] = f2bf(v.x); o[1] = f2bf(v.y); o[2] = f2bf(v.z); o[3] = f2bf(v.w);
      d[i] = o;
    }
  } else {
    const int sub4 = bidx - 3072;
    const int seg = sub4 >> 8;
    const int sub = sub4 & 255;
    const float* src = (seg == 0) ? WQ : (seg == 1) ? WK : (seg == 2) ? WV : WO;
    unsigned short* dst = (seg == 0) ? WqT : (seg == 1) ? WkT : (seg == 2) ? WvT : WOt;
    const int DK = (seg == 3) ? 1024 : 64;
    int h, dt, ktile;
    if (seg == 3) { h = 0; dt = sub >> 4; ktile = sub & 15; }
    else          { h = sub >> 4; dt = sub & 15; ktile = 0; }
    const int d0 = dt * 64, k0 = ktile * 64;
    const int tx = threadIdx.x & 63, ty = threadIdx.x >> 6;
    const float* s = src + (size_t)h * 1024 * DK;
#pragma unroll
    for (int i = 0; i < 16; ++i) {
      int row = i * 4 + ty;
      tile[row][tx] = s[(size_t)(d0 + row) * DK + k0 + tx];
    }
    __syncthreads();
    unsigned short* dd = dst + (size_t)h * DK * 1024;
#pragma unroll
    for (int i = 0; i < 16; ++i) {
      int kk = i * 4 + ty;
      dd[(size_t)(k0 + kk) * 1024 + d0 + tx] = f2bf(tile[tx][kk]);
    }
  }
}

// ---------------------------------------------------------------------------
// GEMM body: C[m][n] = sum_k A[m][k] * Bt[n][k], K=1024, tile 128x128.
// All-bf16, global_load_lds width-16 both sides. SM = single 32KB buffer
// (As = SM, Bs = SM+8192); after the k-loop it is reused as the C-tile for
// the coalesced epilogue (modes 1/2). Mode 0 keeps direct f32 stores.
// CMODE 0: C f32 [M][1024]
// CMODE 1: C bf16 per-head [B,H,T,64]   (row = b*T+t, col = h*64+k)
// CMODE 2: C bf16 VhT [B,H,64,T]        (row = h*64+v, col = b*T+t)
// ---------------------------------------------------------------------------
template <int CMODE>
__device__ __forceinline__ void gemm_body(
    unsigned short* __restrict__ SM,
    const unsigned short* __restrict__ A, const unsigned short* __restrict__ Bt,
    void* __restrict__ C, int bid, int nTilesN, float scale) {
  unsigned short* As = SM;
  unsigned short* Bs = SM + 8192;
  const int bm = bid / nTilesN, bn = bid % nTilesN;
  const int m0 = bm * 128, n0 = bn * 128;
  const int tid = threadIdx.x;
  const int wave = tid >> 6, lane = tid & 63;
  const int wr = wave >> 1, wc = wave & 1;

  f32x4 acc[4][4];
#pragma unroll
  for (int m = 0; m < 4; ++m)
#pragma unroll
    for (int n = 0; n < 4; ++n) acc[m][n] = 0.f;

  const int soff = wave * 1024 + lane * 16;
  const char* Afr = (const char*)As + (wr * 64 + (lane & 15)) * 128 + (lane >> 4) * 16;
  const char* Bfr = (const char*)Bs + (wc * 64 + (lane & 15)) * 128 + (lane >> 4) * 16;

  for (int kt = 0; kt < 16; ++kt) {
    __syncthreads();
#pragma unroll
    for (int i = 0; i < 4; ++i) {
      int o2 = i * 4096 + soff;
      int row = o2 >> 7, colb = o2 & 127;
      gload_lds16((const char*)(A + (size_t)(m0 + row) * 1024 + kt * 64) + colb,
                  (char*)As + i * 4096 + wave * 1024);
      gload_lds16((const char*)(Bt + (size_t)(n0 + row) * 1024 + kt * 64) + colb,
                  (char*)Bs + i * 4096 + wave * 1024);
    }
    __syncthreads();
#pragma unroll
    for (int kk = 0; kk < 2; ++kk) {
      bf16x8 af[4], bf[4];
#pragma unroll
      for (int m = 0; m < 4; ++m) af[m] = *(const bf16x8*)(Afr + m * 2048 + kk * 64);
#pragma unroll
      for (int n = 0; n < 4; ++n) bf[n] = *(const bf16x8*)(Bfr + n * 2048 + kk * 64);
#pragma unroll
      for (int m = 0; m < 4; ++m)
#pragma unroll
        for (int n = 0; n < 4; ++n) acc[m][n] = MFMA16(af[m], bf[n], acc[m][n]);
    }
  }

  if constexpr (CMODE == 0) {
    const int rbase = m0 + wr * 64 + ((lane >> 4) << 2);
    const int cbase = n0 + wc * 64 + (lane & 15);
#pragma unroll
    for (int m = 0; m < 4; ++m)
#pragma unroll
      for (int n = 0; n < 4; ++n)
#pragma unroll
        for (int r = 0; r < 4; ++r) {
          int row = rbase + m * 16 + r;
          int col = cbase + n * 16;
          ((float*)C)[(size_t)row * 1024 + col] = acc[m][n][r] * scale;
        }
  } else {
    // ---- coalesced epilogue: acc -> LDS (swizzled) -> 16B global stores ----
    __syncthreads();                         // all waves done reading As/Bs
    const int rb = wr * 64 + ((lane >> 4) << 2);   // LDS row base
    const int cb = wc * 64 + (lane & 15);          // LDS col base
#pragma unroll
    for (int m = 0; m < 4; ++m)
#pragma unroll
      for (int n = 0; n < 4; ++n)
#pragma unroll
        for (int r = 0; r < 4; ++r) {
          int row = rb + m * 16 + r;
          int col = cb + n * 16;
          int byte = row * 256 + ((col * 2) ^ ((row & 7) << 4));
          *(unsigned short*)((char*)SM + byte) = f2bf(acc[m][n][r] * scale);
        }
    __syncthreads();
#pragma unroll
    for (int it = 0; it < 8; ++it) {
      int p = it * 256 + tid;                // piece: 16B of a tile row
      int row = p >> 4, q = p & 15;
      int byte = row * 256 + ((q * 16) ^ ((row & 7) << 4));
      u32x4 v = *(const u32x4*)((const char*)SM + byte);
      int row_g = m0 + row;
      size_t dst;
      if constexpr (CMODE == 1) {
        int b = row_g >> 11, t = row_g & 2047;
        int h = (n0 >> 6) + (q >> 3), k = (q & 7) * 8;
        dst = (((size_t)(b * H_ + h) * T_) + t) * 64 + k;
      } else {
        int h = row_g >> 6, vv = row_g & 63;
        int b = n0 >> 11, t = (n0 & 2047) + q * 8;
        dst = (((size_t)(b * H_ + h) * 64) + vv) * T_ + t;
      }
      *(u32x4*)((unsigned short*)C + dst) = v;
    }
  }
}

// All three projection GEMMs in ONE dispatch (1536 blocks), XCD-swizzled.
__global__ __launch_bounds__(256) void gemm_proj3(
    const unsigned short* __restrict__ Qbf, const unsigned short* __restrict__ WqT,
    unsigned short* __restrict__ Qh,
    const unsigned short* __restrict__ Kbf, const unsigned short* __restrict__ WkT,
    unsigned short* __restrict__ Kh,
    const unsigned short* __restrict__ WvT, const unsigned short* __restrict__ Vbf,
    unsigned short* __restrict__ VhT, float qscale) {
  __shared__ unsigned short SM[128 * 128];   // 32KB: staging + C-tile epilogue
  const int bid = blockIdx.x;
  const int wid = (bid & 7) * 192 + (bid >> 3);   // 1536/8 = 192, bijective
  const int seg = wid / 512, sub = wid % 512;
  if (seg == 0)      gemm_body<1>(SM, Qbf, WqT, Qh,  sub, 8,  qscale);
  else if (seg == 1) gemm_body<1>(SM, Kbf, WkT, Kh,  sub, 8,  1.0f);
  else               gemm_body<2>(SM, WvT, Vbf, VhT, sub, 64, 1.0f);
}

__global__ __launch_bounds__(256) void gemm_out(
    const unsigned short* __restrict__ A, const unsigned short* __restrict__ Bt,
    float* __restrict__ C) {
  __shared__ unsigned short SM[128 * 128];
  const int bid = blockIdx.x;
  const int wid = (bid & 7) * 64 + (bid >> 3);    // 512/8 = 64, bijective
  gemm_body<0>(SM, A, Bt, C, wid, 8, 1.0f);
}

// ---------------------------------------------------------------------------
// Flash attention (causal), v7c (R14-proven, 88.5us): fused dual-tile inner
// loop, __shfl_xor reductions, T12 in-register P redistribution.
// __launch_bounds__(256,4) REQUIRED: R15 measured natural allocation (VGPR
// 100 + accum) drops a wave class -> occupancy 33->19%, dur 88.5->120us.
// (256,4)'s VGPR=64 split empirically wins on this latency-sensitive chain.
// ---------------------------------------------------------------------------
__global__ __launch_bounds__(256, 4) void attn_fwd(
    const unsigned short* __restrict__ Qh, const unsigned short* __restrict__ Kh,
    const unsigned short* __restrict__ VhT, unsigned short* __restrict__ Abuf) {
  __shared__ unsigned short Ks[2][64 * 64];   // [s][k], swizzled, 8KB each
  __shared__ unsigned short Vs[2][64 * 64];   // [v][s], swizzled, 8KB each

  const int bid = blockIdx.x;
  const int wid = ((bid & 7) << 7) | (bid >> 3);  // XCD swizzle (1024 % 8 == 0)
  const int p  = wid & 15;                   // pair index
  const int bh = wid >> 4;                   // b*H + h
  const int b = bh >> 4, h = bh & 15;
  const int tid = threadIdx.x;
  const int wave = tid >> 6, lane = tid & 63;
  const int lq = lane & 15;
  const int hi = lane >> 4;
  const int nkt = 32 - p;                    // heavy tile KV count

  int q0[2];
  q0[0] = (31 - p) * 64 + wave * 16;         // heavy
  q0[1] = p * 64 + wave * 16;                // light

  const char* Kbase = (const char*)(Kh + (size_t)bh * T_ * 64);
  const char* Vbase = (const char*)(VhT + (size_t)bh * 64 * T_);

  // staging geometry: linear LDS dest, inverse-swizzled global source col
  int srow[2], scol[2], sdst[2];
#pragma unroll
  for (int i = 0; i < 2; ++i) {
    int o = i * 4096 + wave * 1024 + lane * 16;
    srow[i] = o >> 7;
    scol[i] = (o & 127) ^ ((srow[i] & 7) << 4);
    sdst[i] = i * 4096 + wave * 1024;        // wave-uniform dest (HW adds lane*16)
  }

  // Q fragments per tile
  bf16x8 qf[2][2];
#pragma unroll
  for (int j = 0; j < 2; ++j) {
    const unsigned short* qp = Qh + ((size_t)bh * T_ + q0[j] + lq) * 64 + hi * 8;
    qf[j][0] = *(const bf16x8*)qp;
    qf[j][1] = *(const bf16x8*)(qp + 32);
  }

  f32x4 o[2][4];
#pragma unroll
  for (int j = 0; j < 2; ++j)
#pragma unroll
    for (int n = 0; n < 4; ++n) o[j][n] = 0.f;
  float m_run[2] = {-1e30f, -1e30f}, l_run[2] = {0.f, 0.f};

  auto stage = [&](int buf, int kt) {
#pragma unroll
    for (int i = 0; i < 2; ++i) {
      gload_lds16(Kbase + (size_t)(kt * 64 + srow[i]) * 128 + scol[i],
                  (char*)Ks[buf] + sdst[i]);
      gload_lds16(Vbase + (size_t)srow[i] * (T_ * 2) + kt * 128 + scol[i],
                  (char*)Vs[buf] + sdst[i]);
    }
  };

  // softmax + pack for one q-tile — R11/R14-proven __shfl_xor semantics
  auto softmax = [&](f32x4 (&sc)[4], f32x4 (&oj)[4], float& mr, float& lr,
                     int q0j, int s0, unsigned (&pk)[4][2]) {
    if (s0 + 63 > q0j) {                     // diagonal tile: element mask
      int qg = q0j + lq;
#pragma unroll
      for (int c = 0; c < 4; ++c)
#pragma unroll
        for (int r = 0; r < 4; ++r) {
          int sg = s0 + c * 16 + hi * 4 + r;
          if (sg > qg) sc[c][r] = -1e30f;
        }
    }
    float pmax = sc[0][0];
#pragma unroll
    for (int c = 0; c < 4; ++c)
#pragma unroll
      for (int r = 0; r < 4; ++r) pmax = fmaxf(pmax, sc[c][r]);
    pmax = fmaxf(pmax, __shfl_xor(pmax, 16));
    pmax = fmaxf(pmax, __shfl_xor(pmax, 32));

    if (!__all(pmax - mr <= 8.f)) {          // defer-max (T13): usually skip
      float mnew = fmaxf(mr, pmax);
      float corr = __builtin_amdgcn_exp2f(mr - mnew);
      float cr[4];
#pragma unroll
      for (int r = 0; r < 4; ++r) cr[r] = __shfl(corr, hi * 4 + r);
#pragma unroll
      for (int n = 0; n < 4; ++n)
#pragma unroll
        for (int r = 0; r < 4; ++r) oj[n][r] *= cr[r];
      lr *= corr;
      mr = mnew;
    }

    float psum = 0.f;
#pragma unroll
    for (int c = 0; c < 4; ++c) {
      float e0 = __builtin_amdgcn_exp2f(sc[c][0] - mr);
      float e1 = __builtin_amdgcn_exp2f(sc[c][1] - mr);
      float e2 = __builtin_amdgcn_exp2f(sc[c][2] - mr);
      float e3 = __builtin_amdgcn_exp2f(sc[c][3] - mr);
      psum += (e0 + e1) + (e2 + e3);
      pk[c][0] = pack_bf2(e0, e1);
      pk[c][1] = pack_bf2(e2, e3);
    }
    psum += __shfl_xor(psum, 16);
    psum += __shfl_xor(psum, 32);
    lr += psum;
  };

  // T12: build PV A-fragment dwords from packed P via permlane swaps
  // (distinct-value operands; end-to-end verified R7-R11/R14)
  auto mkpa = [&](unsigned (&pk)[4][2], int ks) -> bf16x8 {
    unsigned a0 = pk[2 * ks][0], b0 = pk[2 * ks + 1][0];
    unsigned a1 = pk[2 * ks][1], b1 = pk[2 * ks + 1][1];
    asm("v_permlane32_swap_b32 %0, %1" : "+v"(a0), "+v"(b0));
    asm("v_permlane16_swap_b32 %0, %1" : "+v"(a0), "+v"(b0));
    asm("v_permlane32_swap_b32 %0, %1" : "+v"(a1), "+v"(b1));
    asm("v_permlane16_swap_b32 %0, %1" : "+v"(a1), "+v"(b1));
    u32x4 pau;
    pau[0] = a0; pau[1] = a1; pau[2] = b0; pau[3] = b1;
    return __builtin_bit_cast(bf16x8, pau);
  };

  // prologue: stage tile 0
  stage(0, 0);
  asm volatile("s_waitcnt vmcnt(0)" ::: "memory");
  __builtin_amdgcn_s_barrier();

  int cur = 0;
  for (int kt = 0; kt < nkt; ++kt) {
    const int s0 = kt * 64;
    if (kt + 1 < nkt) stage(cur ^ 1, kt + 1);   // prefetch overlaps compute

    const char* KsB = (const char*)Ks[cur];
    const char* VsB = (const char*)Vs[cur];
    const bool act1 = (kt <= p);             // light tile active (block-uniform)

    // ---- fused QK^T: K fragments read once, feed both q-tiles ----
    f32x4 sc0[4], sc1[4];
    __builtin_amdgcn_s_setprio(1);
#pragma unroll
    for (int c = 0; c < 4; ++c) {
      int r = c * 16 + lq;
      const char* kb = KsB + r * 128;
      int sw = (r & 7) << 4;
      bf16x8 ka0 = *(const bf16x8*)(kb + ((hi * 16) ^ sw));
      bf16x8 ka1 = *(const bf16x8*)(kb + ((64 + hi * 16) ^ sw));
      f32x4 z0 = 0.f;
      z0 = MFMA16(ka0, qf[0][0], z0);
      sc0[c] = MFMA16(ka1, qf[0][1], z0);
      if (act1) {
        f32x4 z1 = 0.f;
        z1 = MFMA16(ka0, qf[1][0], z1);
        sc1[c] = MFMA16(ka1, qf[1][1], z1);
      }
    }
    __builtin_amdgcn_s_setprio(0);

    // ---- softmax per tile -> packed P in registers ----
    unsigned pk0[4][2], pk1[4][2];
    softmax(sc0, o[0], m_run[0], l_run[0], q0[0], s0, pk0);
    if (act1) softmax(sc1, o[1], m_run[1], l_run[1], q0[1], s0, pk1);

    // ---- fused PV: V fragments read once, feed both q-tiles ----
    __builtin_amdgcn_s_setprio(1);
#pragma unroll
    for (int ks = 0; ks < 2; ++ks) {
      bf16x8 pa0 = mkpa(pk0, ks);
      bf16x8 pa1;
      if (act1) pa1 = mkpa(pk1, ks);
#pragma unroll
      for (int n = 0; n < 4; ++n) {
        int rv = n * 16 + lq;
        bf16x8 vb = *(const bf16x8*)(VsB + rv * 128 +
                                     ((ks * 64 + hi * 16) ^ ((rv & 7) << 4)));
        o[0][n] = MFMA16(pa0, vb, o[0][n]);
        if (act1) o[1][n] = MFMA16(pa1, vb, o[1][n]);
      }
    }
    __builtin_amdgcn_s_setprio(0);

    // tile boundary: drain prefetch, sync all waves
    asm volatile("s_waitcnt vmcnt(0)" ::: "memory");
    __builtin_amdgcn_s_barrier();
    cur ^= 1;
  }

  // finalize: divide by l, write A [b*T+t][h*64+v] bf16
#pragma unroll
  for (int j = 0; j < 2; ++j) {
    float inv[4];
#pragma unroll
    for (int r = 0; r < 4; ++r)
      inv[r] = 1.0f / __shfl(l_run[j], hi * 4 + r);
#pragma unroll
    for (int r = 0; r < 4; ++r) {
      int t = q0[j] + hi * 4 + r;
      size_t base = ((size_t)b * T_ + t) * 1024 + h * 64 + lq;
#pragma unroll
      for (int n = 0; n < 4; ++n)
        Abuf[base + n * 16] = f2bf(o[j][n][r] * inv[r]);
    }
  }
}

// ---------------------------------------------------------------------------
extern "C" void kernel_launch(void* const* d_in, const int* in_sizes, int n_in,
                              void* d_out, int out_size, void* d_ws, size_t ws_size,
                              hipStream_t stream) {
  (void)in_sizes; (void)n_in; (void)out_size; (void)ws_size;
  const float* Q  = (const float*)d_in[0];
  const float* K  = (const float*)d_in[1];
  const float* V  = (const float*)d_in[2];
  const float* WQ = (const float*)d_in[3];
  const float* WK = (const float*)d_in[4];
  const float* WV = (const float*)d_in[5];
  const float* WO = (const float*)d_in[6];
  float* out = (float*)d_out;
  char* ws = (char*)d_ws;

  const size_t SZ_ACT = (size_t)8192 * 1024 * 2;  // 16.78 MB
  const size_t SZ_W   = (size_t)1024 * 1024 * 2;  //  2.10 MB
  unsigned short* Qbf = (unsigned short*)(ws);
  unsigned short* Kbf = (unsigned short*)(ws + SZ_ACT);
  unsigned short* Vbf = (unsigned short*)(ws + 2 * SZ_ACT);
  unsigned short* WqT = (unsigned short*)(ws + 3 * SZ_ACT);
  unsigned short* WkT = (unsigned short*)(ws + 3 * SZ_ACT + SZ_W);
  unsigned short* WvT = (unsigned short*)(ws + 3 * SZ_ACT + 2 * SZ_W);
  unsigned short* WOt = (unsigned short*)(ws + 3 * SZ_ACT + 3 * SZ_W);
  unsigned short* Qh  = (unsigned short*)(ws + 3 * SZ_ACT + 4 * SZ_W);
  unsigned short* Kh  = (unsigned short*)(ws + 4 * SZ_ACT + 4 * SZ_W);
  unsigned short* VhT = (unsigned short*)(ws + 5 * SZ_ACT + 4 * SZ_W);
  unsigned short* Abuf = Qbf;  // Qbf dead after Q projection

  // 1) convert activations + transpose weights (one dispatch)
  prep<<<4096, 256, 0, stream>>>((const float4*)Q, (const float4*)K,
                                 (const float4*)V, (u16x4*)Qbf, (u16x4*)Kbf,
                                 (u16x4*)Vbf, WQ, WK, WV, WO,
                                 WqT, WkT, WvT, WOt);

  // 2) projections (one dispatch, all-bf16; Q scaled by log2(e)/sqrt(dk))
  const float qscale = 1.4426950408889634f / 8.0f;
  gemm_proj3<<<1536, 256, 0, stream>>>(Qbf, WqT, Qh, Kbf, WkT, Kh,
                                       WvT, Vbf, VhT, qscale);

  // 3) causal flash attention (fused dual-tile, (256,4) per R14/R15 A/B)
  attn_fwd<<<1024, 256, 0, stream>>>(Qh, Kh, VhT, Abuf);

  // 4) output projection -> f32
  gemm_out<<<512, 256, 0, stream>>>(Abuf, WOt, out);
}

// Round 17
// 204.705 us; speedup vs baseline: 1.2207x; 1.0552x over previous
//
#include <hip/hip_runtime.h>
#include <hip/hip_bf16.h>

// Problem constants (fixed)
#define B_ 4
#define T_ 2048
#define D_ 1024
#define H_ 16
// DK = DV = 64

typedef __attribute__((ext_vector_type(8))) short bf16x8;
typedef __attribute__((ext_vector_type(4))) float f32x4;
typedef __attribute__((ext_vector_type(4))) unsigned short u16x4;
typedef __attribute__((ext_vector_type(4))) unsigned int u32x4;

__device__ __forceinline__ unsigned short f2bf(float x) {
  union { float f; unsigned u; } v; v.f = x;
  unsigned r = v.u + 0x7fffu + ((v.u >> 16) & 1u);   // RNE
  return (unsigned short)(r >> 16);
}

__device__ __forceinline__ unsigned pack_bf2(float a, float b) {
  __hip_bfloat162 h = __float22bfloat162_rn(float2{a, b});
  union { __hip_bfloat162 h; unsigned u; } cv; cv.h = h; return cv.u;
}

__device__ __forceinline__ void gload_lds16(const void* g, void* l) {
  __builtin_amdgcn_global_load_lds(
      (const __attribute__((address_space(1))) unsigned int*)g,
      (__attribute__((address_space(3))) unsigned int*)l, 16, 0, 0);
}

#define MFMA16(a, b, c) __builtin_amdgcn_mfma_f32_16x16x32_bf16((a), (b), (c), 0, 0, 0)

// ---------------------------------------------------------------------------
// prep: activation f32->bf16 convert (3072 blocks) + weight transposes
// (1024 blocks) in ONE dispatch.
// ---------------------------------------------------------------------------
__global__ __launch_bounds__(256) void prep(
    const float4* __restrict__ Q, const float4* __restrict__ K,
    const float4* __restrict__ V, u16x4* __restrict__ Qb,
    u16x4* __restrict__ Kb, u16x4* __restrict__ Vb,
    const float* __restrict__ WQ, const float* __restrict__ WK,
    const float* __restrict__ WV, const float* __restrict__ WO,
    unsigned short* __restrict__ WqT, unsigned short* __restrict__ WkT,
    unsigned short* __restrict__ WvT, unsigned short* __restrict__ WOt) {
  __shared__ float tile[64][65];
  const int bidx = blockIdx.x;
  if (bidx < 3072) {
    const int seg = bidx >> 10;
    const int sb  = bidx & 1023;
    const float4* s = (seg == 0) ? Q : (seg == 1) ? K : V;
    u16x4* d       = (seg == 0) ? Qb : (seg == 1) ? Kb : Vb;
    int i = sb * 256 + threadIdx.x;
#pragma unroll
    for (int it = 0; it < 8; ++it, i += 262144) {   // n4 = 2097152
      float4 v = s[i];
      u16x4 o;
      o[0] = f2bf(v.x); o[1] = f2bf(v.y); o[2] = f2bf(v.z); o[3] = f2bf(v.w);
      d[i] = o;
    }
  } else {
    const int sub4 = bidx - 3072;
    const int seg = sub4 >> 8;
    const int sub = sub4 & 255;
    const float* src = (seg == 0) ? WQ : (seg == 1) ? WK : (seg == 2) ? WV : WO;
    unsigned short* dst = (seg == 0) ? WqT : (seg == 1) ? WkT : (seg == 2) ? WvT : WOt;
    const int DK = (seg == 3) ? 1024 : 64;
    int h, dt, ktile;
    if (seg == 3) { h = 0; dt = sub >> 4; ktile = sub & 15; }
    else          { h = sub >> 4; dt = sub & 15; ktile = 0; }
    const int d0 = dt * 64, k0 = ktile * 64;
    const int tx = threadIdx.x & 63, ty = threadIdx.x >> 6;
    const float* s = src + (size_t)h * 1024 * DK;
#pragma unroll
    for (int i = 0; i < 16; ++i) {
      int row = i * 4 + ty;
      tile[row][tx] = s[(size_t)(d0 + row) * DK + k0 + tx];
    }
    __syncthreads();
    unsigned short* dd = dst + (size_t)h * DK * 1024;
#pragma unroll
    for (int i = 0; i < 16; ++i) {
      int kk = i * 4 + ty;
      dd[(size_t)(k0 + kk) * 1024 + d0 + tx] = f2bf(tile[tx][kk]);
    }
  }
}

// ---------------------------------------------------------------------------
// GEMM body: C[m][n] = sum_k A[m][k] * Bt[n][k], K=1024, tile 128x128.
// All-bf16, global_load_lds width-16 both sides. SM = single 32KB buffer
// (As = SM, Bs = SM+8192); after the k-loop it is reused as the C-tile for
// the coalesced epilogue (modes 1/2). Mode 0 keeps direct f32 stores.
// Launch bound (256,4): arch-VGPR <= 64 + 64 AGPR acc = 128/wave -> 4
// blocks/CU. The k-loop live set (af/bf 32 + addr ~16) fits 64 arch regs
// because global_load_lds stages LDS-direct (no data through registers).
// [R8's (256,5) demanded 48 -> acc spill; R9's f32-staging variant needed
// staging regs; neither applies to this bf16+gload_lds body.]
// CMODE 0: C f32 [M][1024]
// CMODE 1: C bf16 per-head [B,H,T,64]   (row = b*T+t, col = h*64+k)
// CMODE 2: C bf16 VhT [B,H,64,T]        (row = h*64+v, col = b*T+t)
// ---------------------------------------------------------------------------
template <int CMODE>
__device__ __forceinline__ void gemm_body(
    unsigned short* __restrict__ SM,
    const unsigned short* __restrict__ A, const unsigned short* __restrict__ Bt,
    void* __restrict__ C, int bid, int nTilesN, float scale) {
  unsigned short* As = SM;
  unsigned short* Bs = SM + 8192;
  const int bm = bid / nTilesN, bn = bid % nTilesN;
  const int m0 = bm * 128, n0 = bn * 128;
  const int tid = threadIdx.x;
  const int wave = tid >> 6, lane = tid & 63;
  const int wr = wave >> 1, wc = wave & 1;

  f32x4 acc[4][4];
#pragma unroll
  for (int m = 0; m < 4; ++m)
#pragma unroll
    for (int n = 0; n < 4; ++n) acc[m][n] = 0.f;

  const int soff = wave * 1024 + lane * 16;
  const char* Afr = (const char*)As + (wr * 64 + (lane & 15)) * 128 + (lane >> 4) * 16;
  const char* Bfr = (const char*)Bs + (wc * 64 + (lane & 15)) * 128 + (lane >> 4) * 16;

  for (int kt = 0; kt < 16; ++kt) {
    __syncthreads();
#pragma unroll
    for (int i = 0; i < 4; ++i) {
      int o2 = i * 4096 + soff;
      int row = o2 >> 7, colb = o2 & 127;
      gload_lds16((const char*)(A + (size_t)(m0 + row) * 1024 + kt * 64) + colb,
                  (char*)As + i * 4096 + wave * 1024);
      gload_lds16((const char*)(Bt + (size_t)(n0 + row) * 1024 + kt * 64) + colb,
                  (char*)Bs + i * 4096 + wave * 1024);
    }
    __syncthreads();
#pragma unroll
    for (int kk = 0; kk < 2; ++kk) {
      bf16x8 af[4], bf[4];
#pragma unroll
      for (int m = 0; m < 4; ++m) af[m] = *(const bf16x8*)(Afr + m * 2048 + kk * 64);
#pragma unroll
      for (int n = 0; n < 4; ++n) bf[n] = *(const bf16x8*)(Bfr + n * 2048 + kk * 64);
#pragma unroll
      for (int m = 0; m < 4; ++m)
#pragma unroll
        for (int n = 0; n < 4; ++n) acc[m][n] = MFMA16(af[m], bf[n], acc[m][n]);
    }
  }

  if constexpr (CMODE == 0) {
    const int rbase = m0 + wr * 64 + ((lane >> 4) << 2);
    const int cbase = n0 + wc * 64 + (lane & 15);
#pragma unroll
    for (int m = 0; m < 4; ++m)
#pragma unroll
      for (int n = 0; n < 4; ++n)
#pragma unroll
        for (int r = 0; r < 4; ++r) {
          int row = rbase + m * 16 + r;
          int col = cbase + n * 16;
          ((float*)C)[(size_t)row * 1024 + col] = acc[m][n][r] * scale;
        }
  } else {
    // ---- coalesced epilogue: acc -> LDS (swizzled) -> 16B global stores ----
    __syncthreads();                         // all waves done reading As/Bs
    const int rb = wr * 64 + ((lane >> 4) << 2);   // LDS row base
    const int cb = wc * 64 + (lane & 15);          // LDS col base
#pragma unroll
    for (int m = 0; m < 4; ++m)
#pragma unroll
      for (int n = 0; n < 4; ++n)
#pragma unroll
        for (int r = 0; r < 4; ++r) {
          int row = rb + m * 16 + r;
          int col = cb + n * 16;
          int byte = row * 256 + ((col * 2) ^ ((row & 7) << 4));
          *(unsigned short*)((char*)SM + byte) = f2bf(acc[m][n][r] * scale);
        }
    __syncthreads();
#pragma unroll
    for (int it = 0; it < 8; ++it) {
      int p = it * 256 + tid;                // piece: 16B of a tile row
      int row = p >> 4, q = p & 15;
      int byte = row * 256 + ((q * 16) ^ ((row & 7) << 4));
      u32x4 v = *(const u32x4*)((const char*)SM + byte);
      int row_g = m0 + row;
      size_t dst;
      if constexpr (CMODE == 1) {
        int b = row_g >> 11, t = row_g & 2047;
        int h = (n0 >> 6) + (q >> 3), k = (q & 7) * 8;
        dst = (((size_t)(b * H_ + h) * T_) + t) * 64 + k;
      } else {
        int h = row_g >> 6, vv = row_g & 63;
        int b = n0 >> 11, t = (n0 & 2047) + q * 8;
        dst = (((size_t)(b * H_ + h) * 64) + vv) * T_ + t;
      }
      *(u32x4*)((unsigned short*)C + dst) = v;
    }
  }
}

// All three projection GEMMs in ONE dispatch (1536 blocks), XCD-swizzled.
__global__ __launch_bounds__(256, 4) void gemm_proj3(
    const unsigned short* __restrict__ Qbf, const unsigned short* __restrict__ WqT,
    unsigned short* __restrict__ Qh,
    const unsigned short* __restrict__ Kbf, const unsigned short* __restrict__ WkT,
    unsigned short* __restrict__ Kh,
    const unsigned short* __restrict__ WvT, const unsigned short* __restrict__ Vbf,
    unsigned short* __restrict__ VhT, float qscale) {
  __shared__ unsigned short SM[128 * 128];   // 32KB: staging + C-tile epilogue
  const int bid = blockIdx.x;
  const int wid = (bid & 7) * 192 + (bid >> 3);   // 1536/8 = 192, bijective
  const int seg = wid / 512, sub = wid % 512;
  if (seg == 0)      gemm_body<1>(SM, Qbf, WqT, Qh,  sub, 8,  qscale);
  else if (seg == 1) gemm_body<1>(SM, Kbf, WkT, Kh,  sub, 8,  1.0f);
  else               gemm_body<2>(SM, WvT, Vbf, VhT, sub, 64, 1.0f);
}

__global__ __launch_bounds__(256, 4) void gemm_out(
    const unsigned short* __restrict__ A, const unsigned short* __restrict__ Bt,
    float* __restrict__ C) {
  __shared__ unsigned short SM[128 * 128];
  const int bid = blockIdx.x;
  const int wid = (bid & 7) * 64 + (bid >> 3);    // 512/8 = 64, bijective
  gemm_body<0>(SM, A, Bt, C, wid, 8, 1.0f);
}

// ---------------------------------------------------------------------------
// Flash attention (causal), v7c (R14-proven, 88.5us): fused dual-tile inner
// loop, __shfl_xor reductions, T12 in-register P redistribution.
// __launch_bounds__(256,4) REQUIRED: R15 measured natural allocation (VGPR
// 100 + accum) drops a wave class -> occupancy 33->19%, dur 88.5->120us.
// FROZEN this round (single-variable experiment on the GEMMs).
// ---------------------------------------------------------------------------
__global__ __launch_bounds__(256, 4) void attn_fwd(
    const unsigned short* __restrict__ Qh, const unsigned short* __restrict__ Kh,
    const unsigned short* __restrict__ VhT, unsigned short* __restrict__ Abuf) {
  __shared__ unsigned short Ks[2][64 * 64];   // [s][k], swizzled, 8KB each
  __shared__ unsigned short Vs[2][64 * 64];   // [v][s], swizzled, 8KB each

  const int bid = blockIdx.x;
  const int wid = ((bid & 7) << 7) | (bid >> 3);  // XCD swizzle (1024 % 8 == 0)
  const int p  = wid & 15;                   // pair index
  const int bh = wid >> 4;                   // b*H + h
  const int b = bh >> 4, h = bh & 15;
  const int tid = threadIdx.x;
  const int wave = tid >> 6, lane = tid & 63;
  const int lq = lane & 15;
  const int hi = lane >> 4;
  const int nkt = 32 - p;                    // heavy tile KV count

  int q0[2];
  q0[0] = (31 - p) * 64 + wave * 16;         // heavy
  q0[1] = p * 64 + wave * 16;                // light

  const char* Kbase = (const char*)(Kh + (size_t)bh * T_ * 64);
  const char* Vbase = (const char*)(VhT + (size_t)bh * 64 * T_);

  // staging geometry: linear LDS dest, inverse-swizzled global source col
  int srow[2], scol[2], sdst[2];
#pragma unroll
  for (int i = 0; i < 2; ++i) {
    int o = i * 4096 + wave * 1024 + lane * 16;
    srow[i] = o >> 7;
    scol[i] = (o & 127) ^ ((srow[i] & 7) << 4);
    sdst[i] = i * 4096 + wave * 1024;        // wave-uniform dest (HW adds lane*16)
  }

  // Q fragments per tile
  bf16x8 qf[2][2];
#pragma unroll
  for (int j = 0; j < 2; ++j) {
    const unsigned short* qp = Qh + ((size_t)bh * T_ + q0[j] + lq) * 64 + hi * 8;
    qf[j][0] = *(const bf16x8*)qp;
    qf[j][1] = *(const bf16x8*)(qp + 32);
  }

  f32x4 o[2][4];
#pragma unroll
  for (int j = 0; j < 2; ++j)
#pragma unroll
    for (int n = 0; n < 4; ++n) o[j][n] = 0.f;
  float m_run[2] = {-1e30f, -1e30f}, l_run[2] = {0.f, 0.f};

  auto stage = [&](int buf, int kt) {
#pragma unroll
    for (int i = 0; i < 2; ++i) {
      gload_lds16(Kbase + (size_t)(kt * 64 + srow[i]) * 128 + scol[i],
                  (char*)Ks[buf] + sdst[i]);
      gload_lds16(Vbase + (size_t)srow[i] * (T_ * 2) + kt * 128 + scol[i],
                  (char*)Vs[buf] + sdst[i]);
    }
  };

  // softmax + pack for one q-tile — R11/R14-proven __shfl_xor semantics
  auto softmax = [&](f32x4 (&sc)[4], f32x4 (&oj)[4], float& mr, float& lr,
                     int q0j, int s0, unsigned (&pk)[4][2]) {
    if (s0 + 63 > q0j) {                     // diagonal tile: element mask
      int qg = q0j + lq;
#pragma unroll
      for (int c = 0; c < 4; ++c)
#pragma unroll
        for (int r = 0; r < 4; ++r) {
          int sg = s0 + c * 16 + hi * 4 + r;
          if (sg > qg) sc[c][r] = -1e30f;
        }
    }
    float pmax = sc[0][0];
#pragma unroll
    for (int c = 0; c < 4; ++c)
#pragma unroll
      for (int r = 0; r < 4; ++r) pmax = fmaxf(pmax, sc[c][r]);
    pmax = fmaxf(pmax, __shfl_xor(pmax, 16));
    pmax = fmaxf(pmax, __shfl_xor(pmax, 32));

    if (!__all(pmax - mr <= 8.f)) {          // defer-max (T13): usually skip
      float mnew = fmaxf(mr, pmax);
      float corr = __builtin_amdgcn_exp2f(mr - mnew);
      float cr[4];
#pragma unroll
      for (int r = 0; r < 4; ++r) cr[r] = __shfl(corr, hi * 4 + r);
#pragma unroll
      for (int n = 0; n < 4; ++n)
#pragma unroll
        for (int r = 0; r < 4; ++r) oj[n][r] *= cr[r];
      lr *= corr;
      mr = mnew;
    }

    float psum = 0.f;
#pragma unroll
    for (int c = 0; c < 4; ++c) {
      float e0 = __builtin_amdgcn_exp2f(sc[c][0] - mr);
      float e1 = __builtin_amdgcn_exp2f(sc[c][1] - mr);
      float e2 = __builtin_amdgcn_exp2f(sc[c][2] - mr);
      float e3 = __builtin_amdgcn_exp2f(sc[c][3] - mr);
      psum += (e0 + e1) + (e2 + e3);
      pk[c][0] = pack_bf2(e0, e1);
      pk[c][1] = pack_bf2(e2, e3);
    }
    psum += __shfl_xor(psum, 16);
    psum += __shfl_xor(psum, 32);
    lr += psum;
  };

  // T12: build PV A-fragment dwords from packed P via permlane swaps
  // (distinct-value operands; end-to-end verified R7-R11/R14)
  auto mkpa = [&](unsigned (&pk)[4][2], int ks) -> bf16x8 {
    unsigned a0 = pk[2 * ks][0], b0 = pk[2 * ks + 1][0];
    unsigned a1 = pk[2 * ks][1], b1 = pk[2 * ks + 1][1];
    asm("v_permlane32_swap_b32 %0, %1" : "+v"(a0), "+v"(b0));
    asm("v_permlane16_swap_b32 %0, %1" : "+v"(a0), "+v"(b0));
    asm("v_permlane32_swap_b32 %0, %1" : "+v"(a1), "+v"(b1));
    asm("v_permlane16_swap_b32 %0, %1" : "+v"(a1), "+v"(b1));
    u32x4 pau;
    pau[0] = a0; pau[1] = a1; pau[2] = b0; pau[3] = b1;
    return __builtin_bit_cast(bf16x8, pau);
  };

  // prologue: stage tile 0
  stage(0, 0);
  asm volatile("s_waitcnt vmcnt(0)" ::: "memory");
  __builtin_amdgcn_s_barrier();

  int cur = 0;
  for (int kt = 0; kt < nkt; ++kt) {
    const int s0 = kt * 64;
    if (kt + 1 < nkt) stage(cur ^ 1, kt + 1);   // prefetch overlaps compute

    const char* KsB = (const char*)Ks[cur];
    const char* VsB = (const char*)Vs[cur];
    const bool act1 = (kt <= p);             // light tile active (block-uniform)

    // ---- fused QK^T: K fragments read once, feed both q-tiles ----
    f32x4 sc0[4], sc1[4];
    __builtin_amdgcn_s_setprio(1);
#pragma unroll
    for (int c = 0; c < 4; ++c) {
      int r = c * 16 + lq;
      const char* kb = KsB + r * 128;
      int sw = (r & 7) << 4;
      bf16x8 ka0 = *(const bf16x8*)(kb + ((hi * 16) ^ sw));
      bf16x8 ka1 = *(const bf16x8*)(kb + ((64 + hi * 16) ^ sw));
      f32x4 z0 = 0.f;
      z0 = MFMA16(ka0, qf[0][0], z0);
      sc0[c] = MFMA16(ka1, qf[0][1], z0);
      if (act1) {
        f32x4 z1 = 0.f;
        z1 = MFMA16(ka0, qf[1][0], z1);
        sc1[c] = MFMA16(ka1, qf[1][1], z1);
      }
    }
    __builtin_amdgcn_s_setprio(0);

    // ---- softmax per tile -> packed P in registers ----
    unsigned pk0[4][2], pk1[4][2];
    softmax(sc0, o[0], m_run[0], l_run[0], q0[0], s0, pk0);
    if (act1) softmax(sc1, o[1], m_run[1], l_run[1], q0[1], s0, pk1);

    // ---- fused PV: V fragments read once, feed both q-tiles ----
    __builtin_amdgcn_s_setprio(1);
#pragma unroll
    for (int ks = 0; ks < 2; ++ks) {
      bf16x8 pa0 = mkpa(pk0, ks);
      bf16x8 pa1;
      if (act1) pa1 = mkpa(pk1, ks);
#pragma unroll
      for (int n = 0; n < 4; ++n) {
        int rv = n * 16 + lq;
        bf16x8 vb = *(const bf16x8*)(VsB + rv * 128 +
                                     ((ks * 64 + hi * 16) ^ ((rv & 7) << 4)));
        o[0][n] = MFMA16(pa0, vb, o[0][n]);
        if (act1) o[1][n] = MFMA16(pa1, vb, o[1][n]);
      }
    }
    __builtin_amdgcn_s_setprio(0);

    // tile boundary: drain prefetch, sync all waves
    asm volatile("s_waitcnt vmcnt(0)" ::: "memory");
    __builtin_amdgcn_s_barrier();
    cur ^= 1;
  }

  // finalize: divide by l, write A [b*T+t][h*64+v] bf16
#pragma unroll
  for (int j = 0; j < 2; ++j) {
    float inv[4];
#pragma unroll
    for (int r = 0; r < 4; ++r)
      inv[r] = 1.0f / __shfl(l_run[j], hi * 4 + r);
#pragma unroll
    for (int r = 0; r < 4; ++r) {
      int t = q0[j] + hi * 4 + r;
      size_t base = ((size_t)b * T_ + t) * 1024 + h * 64 + lq;
#pragma unroll
      for (int n = 0; n < 4; ++n)
        Abuf[base + n * 16] = f2bf(o[j][n][r] * inv[r]);
    }
  }
}

// ---------------------------------------------------------------------------
extern "C" void kernel_launch(void* const* d_in, const int* in_sizes, int n_in,
                              void* d_out, int out_size, void* d_ws, size_t ws_size,
                              hipStream_t stream) {
  (void)in_sizes; (void)n_in; (void)out_size; (void)ws_size;
  const float* Q  = (const float*)d_in[0];
  const float* K  = (const float*)d_in[1];
  const float* V  = (const float*)d_in[2];
  const float* WQ = (const float*)d_in[3];
  const float* WK = (const float*)d_in[4];
  const float* WV = (const float*)d_in[5];
  const float* WO = (const float*)d_in[6];
  float* out = (float*)d_out;
  char* ws = (char*)d_ws;

  const size_t SZ_ACT = (size_t)8192 * 1024 * 2;  // 16.78 MB
  const size_t SZ_W   = (size_t)1024 * 1024 * 2;  //  2.10 MB
  unsigned short* Qbf = (unsigned short*)(ws);
  unsigned short* Kbf = (unsigned short*)(ws + SZ_ACT);
  unsigned short* Vbf = (unsigned short*)(ws + 2 * SZ_ACT);
  unsigned short* WqT = (unsigned short*)(ws + 3 * SZ_ACT);
  unsigned short* WkT = (unsigned short*)(ws + 3 * SZ_ACT + SZ_W);
  unsigned short* WvT = (unsigned short*)(ws + 3 * SZ_ACT + 2 * SZ_W);
  unsigned short* WOt = (unsigned short*)(ws + 3 * SZ_ACT + 3 * SZ_W);
  unsigned short* Qh  = (unsigned short*)(ws + 3 * SZ_ACT + 4 * SZ_W);
  unsigned short* Kh  = (unsigned short*)(ws + 4 * SZ_ACT + 4 * SZ_W);
  unsigned short* VhT = (unsigned short*)(ws + 5 * SZ_ACT + 4 * SZ_W);
  unsigned short* Abuf = Qbf;  // Qbf dead after Q projection

  // 1) convert activations + transpose weights (one dispatch)
  prep<<<4096, 256, 0, stream>>>((const float4*)Q, (const float4*)K,
                                 (const float4*)V, (u16x4*)Qbf, (u16x4*)Kbf,
                                 (u16x4*)Vbf, WQ, WK, WV, WO,
                                 WqT, WkT, WvT, WOt);

  // 2) projections (one dispatch, all-bf16; Q scaled by log2(e)/sqrt(dk))
  const float qscale = 1.4426950408889634f / 8.0f;
  gemm_proj3<<<1536, 256, 0, stream>>>(Qbf, WqT, Qh, Kbf, WkT, Kh,
                                       WvT, Vbf, VhT, qscale);

  // 3) causal flash attention (frozen R14 config)
  attn_fwd<<<1024, 256, 0, stream>>>(Qh, Kh, VhT, Abuf);

  // 4) output projection -> f32
  gemm_out<<<512, 256, 0, stream>>>(Abuf, WOt, out);
}